// Round 2
// baseline (170.762 us; speedup 1.0000x reference)
//
#include <hip/hip_runtime.h>
#include <cmath>

#define B_ 16384
#define S_ 512
#define P_ 1024
#define K_ 8
#define D_ 64
#define H_ 128
#define BT 8     // batch rows per block; bf16-packed tile = 512*4*4B = 8 KB
#define PADU 4   // u32 per LDS row (4 u32 = 8 bf16 batch values), 16B-aligned for b128

typedef float f32x2 __attribute__((ext_vector_type(2)));  // clang vector: OK for nontemporal builtins

// float -> bf16 (RNE, finite inputs) packed helpers
static __device__ __forceinline__ unsigned int rne16(float f) {
  unsigned int u = __float_as_uint(f);
  return (u + 0x7fffu + ((u >> 16) & 1u)) >> 16;
}
static __device__ __forceinline__ float bflo(unsigned int u) { return __uint_as_float(u << 16); }
static __device__ __forceinline__ float bfhi(unsigned int u) { return __uint_as_float(u & 0xffff0000u); }

// ---------------- Kernel A: sklproj[s][h] = dot(skl_emd[s,:], U[h,:]) ----------------
__global__ __launch_bounds__(128) void proj_skl_kernel(
    const float* __restrict__ skl_emd, const float* __restrict__ U,
    float* __restrict__ sklproj) {
  __shared__ float row[D_];
  const int s = blockIdx.x, h = threadIdx.x;
  if (h < D_) row[h] = skl_emd[s * D_ + h];
  __syncthreads();
  float acc = 0.f;
#pragma unroll
  for (int d = 0; d < D_; d++) acc += row[d] * U[h * D_ + d];
  sklproj[s * H_ + h] = acc;
}

// ---------------- Kernel B: att[p][k] = softmax_k( sum_h v[h]*tanh(projP[p][h]+sklproj[g[p][k]][h]) )
__global__ __launch_bounds__(128) void att_kernel(
    const float* __restrict__ plm_emd, const float* __restrict__ W,
    const float* __restrict__ vT, const float* __restrict__ sklproj,
    const int* __restrict__ gidx, float* __restrict__ att) {
  __shared__ float prow[D_];
  __shared__ float red[2][K_];
  const int p = blockIdx.x, h = threadIdx.x;
  if (h < D_) prow[h] = plm_emd[p * D_ + h];
  __syncthreads();
  float pp = 0.f;
#pragma unroll
  for (int d = 0; d < D_; d++) pp += prow[d] * W[h * D_ + d];
  const float v = vT[h];
  int g[K_];
#pragma unroll
  for (int k = 0; k < K_; k++) g[k] = gidx[p * K_ + k];
  float partial[K_];
#pragma unroll
  for (int k = 0; k < K_; k++) partial[k] = v * tanhf(pp + sklproj[g[k] * H_ + h]);
#pragma unroll
  for (int off = 32; off >= 1; off >>= 1)
#pragma unroll
    for (int k = 0; k < K_; k++) partial[k] += __shfl_down(partial[k], off, 64);
  const int wave = h >> 6, lane = h & 63;
  if (lane == 0)
#pragma unroll
    for (int k = 0; k < K_; k++) red[wave][k] = partial[k];
  __syncthreads();
  if (h == 0) {
    float s[K_], m = -1e30f;
#pragma unroll
    for (int k = 0; k < K_; k++) { s[k] = red[0][k] + red[1][k]; m = fmaxf(m, s[k]); }
    float denom = 0.f;
#pragma unroll
    for (int k = 0; k < K_; k++) { s[k] = expf(s[k] - m); denom += s[k]; }
    const float inv = 1.f / denom;
#pragma unroll
    for (int k = 0; k < K_; k++) att[p * K_ + k] = s[k] * inv;
  }
}

// ---------------- Kernel C: out[b][p] = mask[b][p] * sum_k skl_pfc[b][g[p][k]] * att[p][k]
// Transposed bf16-packed LDS tile: rowsT[s] = 4 u32 = 8 batch values. One (p,k)
// gather = ONE ds_read_b128 covering all 8 batch rows.
// R(this): 2 consecutive p per thread -> att/gidx 64B contiguous (4x dwordx4),
// mask/out as 8B vectors (512B per wave-instr), 16 independent gathers per j for
// latency hiding; nontemporal hints on the touch-once streams (skl_pfc, mask, out).
// NO min-waves launch bound: R4/R6 showed caps below ~64 VGPR force scratch
// spills (+50..125 MB HBM traffic). Watch VGPR_Count: if >128 or scratch>0,
// revert to 1-p variant.
__global__ __launch_bounds__(256) void out_kernel(
    const float* __restrict__ skl_pfc, const float* __restrict__ mask,
    const float* __restrict__ att, const int* __restrict__ gidx,
    float* __restrict__ out) {
  __shared__ __align__(16) unsigned int rowsT[S_][PADU];  // 8192 B
  const int t = threadIdx.x;
  const int b0 = blockIdx.x * BT;

  // stage transposed + bf16-pack: s = t, t+256; coalesced reads across lanes per bb
#pragma unroll
  for (int i = 0; i < S_ / 256; i++) {
    const int s = t + i * 256;
    unsigned int pk[PADU];
#pragma unroll
    for (int q = 0; q < PADU; q++) {
      const float f0 = __builtin_nontemporal_load(&skl_pfc[(size_t)(b0 + 2 * q) * S_ + s]);
      const float f1 = __builtin_nontemporal_load(&skl_pfc[(size_t)(b0 + 2 * q + 1) * S_ + s]);
      pk[q] = rne16(f0) | (rne16(f1) << 16);
    }
    *(uint4*)&rowsT[s][0] = make_uint4(pk[0], pk[1], pk[2], pk[3]);
  }
  __syncthreads();

#pragma unroll
  for (int j = 0; j < 2; j++) {
    const int p = 2 * t + j * 512;  // even; p and p+1 handled by this thread
    const float4* ap = (const float4*)(att + (size_t)p * K_);
    const int4* gp = (const int4*)(gidx + (size_t)p * K_);
    const float4 a0 = ap[0], a1 = ap[1], a2 = ap[2], a3 = ap[3];
    const int4 g0 = gp[0], g1 = gp[1], g2 = gp[2], g3 = gp[3];
    const float av0[K_] = {a0.x, a0.y, a0.z, a0.w, a1.x, a1.y, a1.z, a1.w};
    const int gv0[K_] = {g0.x, g0.y, g0.z, g0.w, g1.x, g1.y, g1.z, g1.w};
    const float av1[K_] = {a2.x, a2.y, a2.z, a2.w, a3.x, a3.y, a3.z, a3.w};
    const int gv1[K_] = {g2.x, g2.y, g2.z, g2.w, g3.x, g3.y, g3.z, g3.w};

    f32x2 m2[BT];
#pragma unroll
    for (int bb = 0; bb < BT; bb++)
      m2[bb] = __builtin_nontemporal_load(
          (const f32x2*)&mask[(size_t)(b0 + bb) * P_ + p]);

    float acc0[BT] = {0.f, 0.f, 0.f, 0.f, 0.f, 0.f, 0.f, 0.f};
    float acc1[BT] = {0.f, 0.f, 0.f, 0.f, 0.f, 0.f, 0.f, 0.f};
#pragma unroll
    for (int k = 0; k < K_; k++) {
      const uint4 q0 = *(const uint4*)&rowsT[gv0[k]][0];  // bb 0..7 packed bf16
      const float a = av0[k];
      acc0[0] += bflo(q0.x) * a; acc0[1] += bfhi(q0.x) * a;
      acc0[2] += bflo(q0.y) * a; acc0[3] += bfhi(q0.y) * a;
      acc0[4] += bflo(q0.z) * a; acc0[5] += bfhi(q0.z) * a;
      acc0[6] += bflo(q0.w) * a; acc0[7] += bfhi(q0.w) * a;
    }
#pragma unroll
    for (int k = 0; k < K_; k++) {
      const uint4 q1 = *(const uint4*)&rowsT[gv1[k]][0];
      const float a = av1[k];
      acc1[0] += bflo(q1.x) * a; acc1[1] += bfhi(q1.x) * a;
      acc1[2] += bflo(q1.y) * a; acc1[3] += bfhi(q1.y) * a;
      acc1[4] += bflo(q1.z) * a; acc1[5] += bfhi(q1.z) * a;
      acc1[6] += bflo(q1.w) * a; acc1[7] += bfhi(q1.w) * a;
    }
#pragma unroll
    for (int bb = 0; bb < BT; bb++) {
      f32x2 o;
      o.x = acc0[bb] * m2[bb].x;
      o.y = acc1[bb] * m2[bb].y;
      __builtin_nontemporal_store(o, (f32x2*)&out[(size_t)(b0 + bb) * P_ + p]);
    }
  }
}

extern "C" void kernel_launch(void* const* d_in, const int* in_sizes, int n_in,
                              void* d_out, int out_size, void* d_ws, size_t ws_size,
                              hipStream_t stream) {
  const float* skl_pfc = (const float*)d_in[0];   // [B, S]
  const float* mask    = (const float*)d_in[1];   // [B, P]
  const float* skl_emd = (const float*)d_in[2];   // [S, D]
  const float* plm_emd = (const float*)d_in[3];   // [P, D]
  const float* W       = (const float*)d_in[4];   // [H, D]
  const float* U       = (const float*)d_in[5];   // [H, D]
  const float* vT      = (const float*)d_in[6];   // [1, H]
  const int*   gidx    = (const int*)d_in[7];     // [P, K]
  float* out = (float*)d_out;                     // [B, P]

  float* sklproj = (float*)d_ws;                  // S*H floats = 256 KB
  float* att     = sklproj + S_ * H_;             // P*K floats = 32 KB

  proj_skl_kernel<<<S_, 128, 0, stream>>>(skl_emd, U, sklproj);
  att_kernel<<<P_, 128, 0, stream>>>(plm_emd, W, vT, sklproj, gidx, att);
  out_kernel<<<B_ / BT, 256, 0, stream>>>(skl_pfc, mask, att, gidx, out);
}

// Round 3
// 167.216 us; speedup vs baseline: 1.0212x; 1.0212x over previous
//
#include <hip/hip_runtime.h>
#include <cmath>

#define B_ 16384
#define S_ 512
#define P_ 1024
#define K_ 8
#define D_ 64
#define H_ 128
#define BT 8       // batch rows per tile; bf16-packed tile = 512*4*4B = 8 KB
#define PADU 4     // u32 per LDS row (4 u32 = 8 bf16 batch values), 16B-aligned for b128
#define GRID_C 1024          // blocks for out_kernel; each handles NT/GRID_C = 2 tiles
#define NT (B_ / BT)         // 2048 b-tiles

typedef float f32x2 __attribute__((ext_vector_type(2)));  // clang vector: OK for nontemporal builtins

// float -> bf16 (RNE, finite inputs) packed helpers
static __device__ __forceinline__ unsigned int rne16(float f) {
  unsigned int u = __float_as_uint(f);
  return (u + 0x7fffu + ((u >> 16) & 1u)) >> 16;
}
static __device__ __forceinline__ float bflo(unsigned int u) { return __uint_as_float(u << 16); }
static __device__ __forceinline__ float bfhi(unsigned int u) { return __uint_as_float(u & 0xffff0000u); }

// ---------------- Kernel A: sklproj[s][h] = dot(skl_emd[s,:], U[h,:]) ----------------
__global__ __launch_bounds__(128) void proj_skl_kernel(
    const float* __restrict__ skl_emd, const float* __restrict__ U,
    float* __restrict__ sklproj) {
  __shared__ float row[D_];
  const int s = blockIdx.x, h = threadIdx.x;
  if (h < D_) row[h] = skl_emd[s * D_ + h];
  __syncthreads();
  float acc = 0.f;
#pragma unroll
  for (int d = 0; d < D_; d++) acc += row[d] * U[h * D_ + d];
  sklproj[s * H_ + h] = acc;
}

// ---------------- Kernel B: att[p][k] = softmax_k( sum_h v[h]*tanh(projP[p][h]+sklproj[g[p][k]][h]) )
__global__ __launch_bounds__(128) void att_kernel(
    const float* __restrict__ plm_emd, const float* __restrict__ W,
    const float* __restrict__ vT, const float* __restrict__ sklproj,
    const int* __restrict__ gidx, float* __restrict__ att) {
  __shared__ float prow[D_];
  __shared__ float red[2][K_];
  const int p = blockIdx.x, h = threadIdx.x;
  if (h < D_) prow[h] = plm_emd[p * D_ + h];
  __syncthreads();
  float pp = 0.f;
#pragma unroll
  for (int d = 0; d < D_; d++) pp += prow[d] * W[h * D_ + d];
  const float v = vT[h];
  int g[K_];
#pragma unroll
  for (int k = 0; k < K_; k++) g[k] = gidx[p * K_ + k];
  float partial[K_];
#pragma unroll
  for (int k = 0; k < K_; k++) partial[k] = v * tanhf(pp + sklproj[g[k] * H_ + h]);
#pragma unroll
  for (int off = 32; off >= 1; off >>= 1)
#pragma unroll
    for (int k = 0; k < K_; k++) partial[k] += __shfl_down(partial[k], off, 64);
  const int wave = h >> 6, lane = h & 63;
  if (lane == 0)
#pragma unroll
    for (int k = 0; k < K_; k++) red[wave][k] = partial[k];
  __syncthreads();
  if (h == 0) {
    float s[K_], m = -1e30f;
#pragma unroll
    for (int k = 0; k < K_; k++) { s[k] = red[0][k] + red[1][k]; m = fmaxf(m, s[k]); }
    float denom = 0.f;
#pragma unroll
    for (int k = 0; k < K_; k++) { s[k] = expf(s[k] - m); denom += s[k]; }
    const float inv = 1.f / denom;
#pragma unroll
    for (int k = 0; k < K_; k++) att[p * K_ + k] = s[k] * inv;
  }
}

// ---------------- Kernel C: out[b][p] = mask[b][p] * sum_k skl_pfc[b][g[p][k]] * att[p][k]
// R2 counters: 44 us, HBM 33%, VALU 14.5%, Occ 24% -> latency-bound convoy
// (stage -> barrier -> compute, no overlap). R(this): grid-stride 2 tiles/block,
// double-buffered LDS (2x8KB), prefetch next tile's skl_pfc to regs DURING
// compute of current tile; att/gidx register-cached across tiles (loaded once).
// One barrier per tile; pack(n) vs compute(n-2) separated by barrier(n-1).
// Watch: VGPR>200 or scratch>0 -> revert att/gidx caching.
__global__ __launch_bounds__(256) void out_kernel(
    const float* __restrict__ skl_pfc, const float* __restrict__ mask,
    const float* __restrict__ att, const int* __restrict__ gidx,
    float* __restrict__ out) {
  __shared__ __align__(16) unsigned int rowsT[2][S_][PADU];  // 16384 B
  const int t = threadIdx.x;

  // ---- register-cache att + gidx for this thread's 4 p's (tile-invariant) ----
  // j=0: pA=2t, pB=2t+1 ; j=1: pC=2t+512, pD=2t+513
  float aA[K_], aB[K_], aC[K_], aD[K_];
  int gA[K_], gB[K_], gC[K_], gD[K_];
  {
    const int pj0 = 2 * t, pj1 = 2 * t + 512;
    const float4* ap0 = (const float4*)(att + (size_t)pj0 * K_);
    const int4* gp0 = (const int4*)(gidx + (size_t)pj0 * K_);
    const float4* ap1 = (const float4*)(att + (size_t)pj1 * K_);
    const int4* gp1 = (const int4*)(gidx + (size_t)pj1 * K_);
    const float4 a0 = ap0[0], a1 = ap0[1], a2 = ap0[2], a3 = ap0[3];
    const int4 g0 = gp0[0], g1 = gp0[1], g2 = gp0[2], g3 = gp0[3];
    const float4 a4 = ap1[0], a5 = ap1[1], a6 = ap1[2], a7 = ap1[3];
    const int4 g4 = gp1[0], g5 = gp1[1], g6 = gp1[2], g7 = gp1[3];
    aA[0]=a0.x; aA[1]=a0.y; aA[2]=a0.z; aA[3]=a0.w; aA[4]=a1.x; aA[5]=a1.y; aA[6]=a1.z; aA[7]=a1.w;
    aB[0]=a2.x; aB[1]=a2.y; aB[2]=a2.z; aB[3]=a2.w; aB[4]=a3.x; aB[5]=a3.y; aB[6]=a3.z; aB[7]=a3.w;
    aC[0]=a4.x; aC[1]=a4.y; aC[2]=a4.z; aC[3]=a4.w; aC[4]=a5.x; aC[5]=a5.y; aC[6]=a5.z; aC[7]=a5.w;
    aD[0]=a6.x; aD[1]=a6.y; aD[2]=a6.z; aD[3]=a6.w; aD[4]=a7.x; aD[5]=a7.y; aD[6]=a7.z; aD[7]=a7.w;
    gA[0]=g0.x; gA[1]=g0.y; gA[2]=g0.z; gA[3]=g0.w; gA[4]=g1.x; gA[5]=g1.y; gA[6]=g1.z; gA[7]=g1.w;
    gB[0]=g2.x; gB[1]=g2.y; gB[2]=g2.z; gB[3]=g2.w; gB[4]=g3.x; gB[5]=g3.y; gB[6]=g3.z; gB[7]=g3.w;
    gC[0]=g4.x; gC[1]=g4.y; gC[2]=g4.z; gC[3]=g4.w; gC[4]=g5.x; gC[5]=g5.y; gC[6]=g5.z; gC[7]=g5.w;
    gD[0]=g6.x; gD[1]=g6.y; gD[2]=g6.z; gD[3]=g6.w; gD[4]=g7.x; gD[5]=g7.y; gD[6]=g7.z; gD[7]=g7.w;
  }

  float st[16];  // prefetch staging: [i*8 + b], i in {0,1} -> s = t + 256*i

  // issue prefetch for a tile's skl_pfc rows (NT: touch-once stream)
  auto PREFETCH = [&](int tile) {
    const int b0 = tile * BT;
#pragma unroll
    for (int i = 0; i < 2; i++) {
      const int s = t + i * 256;
#pragma unroll
      for (int b = 0; b < 8; b++)
        st[i * 8 + b] =
            __builtin_nontemporal_load(&skl_pfc[(size_t)(b0 + b) * S_ + s]);
    }
  };

  // bf16-pack staged regs and write transposed tile into LDS buffer
  auto PACK = [&](int buf) {
#pragma unroll
    for (int i = 0; i < 2; i++) {
      const int s = t + i * 256;
      unsigned int pk[PADU];
#pragma unroll
      for (int q = 0; q < PADU; q++)
        pk[q] = rne16(st[i * 8 + 2 * q]) | (rne16(st[i * 8 + 2 * q + 1]) << 16);
      *(uint4*)&rowsT[buf][s][0] = make_uint4(pk[0], pk[1], pk[2], pk[3]);
    }
  };

  auto COMPUTE = [&](int tile, int buf) {
    const int b0 = tile * BT;
#pragma unroll
    for (int j = 0; j < 2; j++) {
      const int p = 2 * t + j * 512;
      const float* av0 = (j == 0) ? aA : aC;
      const float* av1 = (j == 0) ? aB : aD;
      const int* gv0 = (j == 0) ? gA : gC;
      const int* gv1 = (j == 0) ? gB : gD;

      f32x2 m2[BT];
#pragma unroll
      for (int bb = 0; bb < BT; bb++)
        m2[bb] = __builtin_nontemporal_load(
            (const f32x2*)&mask[(size_t)(b0 + bb) * P_ + p]);

      float acc0[BT] = {0.f, 0.f, 0.f, 0.f, 0.f, 0.f, 0.f, 0.f};
      float acc1[BT] = {0.f, 0.f, 0.f, 0.f, 0.f, 0.f, 0.f, 0.f};
#pragma unroll
      for (int k = 0; k < K_; k++) {
        const uint4 q0 = *(const uint4*)&rowsT[buf][gv0[k]][0];
        const float a = av0[k];
        acc0[0] += bflo(q0.x) * a; acc0[1] += bfhi(q0.x) * a;
        acc0[2] += bflo(q0.y) * a; acc0[3] += bfhi(q0.y) * a;
        acc0[4] += bflo(q0.z) * a; acc0[5] += bfhi(q0.z) * a;
        acc0[6] += bflo(q0.w) * a; acc0[7] += bfhi(q0.w) * a;
      }
#pragma unroll
      for (int k = 0; k < K_; k++) {
        const uint4 q1 = *(const uint4*)&rowsT[buf][gv1[k]][0];
        const float a = av1[k];
        acc1[0] += bflo(q1.x) * a; acc1[1] += bfhi(q1.x) * a;
        acc1[2] += bflo(q1.y) * a; acc1[3] += bfhi(q1.y) * a;
        acc1[4] += bflo(q1.z) * a; acc1[5] += bfhi(q1.z) * a;
        acc1[6] += bflo(q1.w) * a; acc1[7] += bfhi(q1.w) * a;
      }
#pragma unroll
      for (int bb = 0; bb < BT; bb++) {
        f32x2 o;
        o.x = acc0[bb] * m2[bb].x;
        o.y = acc1[bb] * m2[bb].y;
        __builtin_nontemporal_store(o, (f32x2*)&out[(size_t)(b0 + bb) * P_ + p]);
      }
    }
  };

  // ---- software pipeline over tiles ----
  int tile = blockIdx.x;
  int buf = 0;
  PREFETCH(tile);
  for (;;) {
    PACK(buf);            // waits on prefetch loads (vmcnt auto)
    __syncthreads();      // tile's LDS buffer ready for all waves
    const int next = tile + GRID_C;
    if (next < NT) PREFETCH(next);  // HBM stream overlaps compute below
    COMPUTE(tile, buf);
    if (next >= NT) break;
    tile = next;
    buf ^= 1;
  }
}

extern "C" void kernel_launch(void* const* d_in, const int* in_sizes, int n_in,
                              void* d_out, int out_size, void* d_ws, size_t ws_size,
                              hipStream_t stream) {
  const float* skl_pfc = (const float*)d_in[0];   // [B, S]
  const float* mask    = (const float*)d_in[1];   // [B, P]
  const float* skl_emd = (const float*)d_in[2];   // [S, D]
  const float* plm_emd = (const float*)d_in[3];   // [P, D]
  const float* W       = (const float*)d_in[4];   // [H, D]
  const float* U       = (const float*)d_in[5];   // [H, D]
  const float* vT      = (const float*)d_in[6];   // [1, H]
  const int*   gidx    = (const int*)d_in[7];     // [P, K]
  float* out = (float*)d_out;                     // [B, P]

  float* sklproj = (float*)d_ws;                  // S*H floats = 256 KB
  float* att     = sklproj + S_ * H_;             // P*K floats = 32 KB

  proj_skl_kernel<<<S_, 128, 0, stream>>>(skl_emd, U, sklproj);
  att_kernel<<<P_, 128, 0, stream>>>(plm_emd, W, vT, sklproj, gidx, att);
  out_kernel<<<GRID_C, 256, 0, stream>>>(skl_pfc, mask, att, gidx, out);
}

// Round 4
// 166.213 us; speedup vs baseline: 1.0274x; 1.0060x over previous
//
#include <hip/hip_runtime.h>
#include <cmath>

#define B_ 16384
#define S_ 512
#define P_ 1024
#define K_ 8
#define D_ 64
#define H_ 128
#define BT 8       // batch rows per tile; bf16-packed tile = 512*4*4B = 8 KB
#define PADU 4     // u32 per LDS row (4 u32 = 8 bf16 batch values), 16B-aligned for b128
#define GRID_C 1024          // blocks for out_kernel; each handles NT/GRID_C = 2 tiles
#define NT (B_ / BT)         // 2048 b-tiles

typedef float f32x2 __attribute__((ext_vector_type(2)));  // clang vector: OK for nontemporal builtins

// float -> bf16 (RNE, finite inputs) packed helpers
static __device__ __forceinline__ unsigned int rne16(float f) {
  unsigned int u = __float_as_uint(f);
  return (u + 0x7fffu + ((u >> 16) & 1u)) >> 16;
}
static __device__ __forceinline__ float bflo(unsigned int u) { return __uint_as_float(u << 16); }
static __device__ __forceinline__ float bfhi(unsigned int u) { return __uint_as_float(u & 0xffff0000u); }

// ---------------- Kernel A: sklproj[s][h] = dot(skl_emd[s,:], U[h,:]) ----------------
// R4: U row read as float4 (was scalar dword stride-256B across lanes = 64
// line-touches per wave-inst x 64 iters). 16 dwordx4 per thread, same sum order.
__global__ __launch_bounds__(128) void proj_skl_kernel(
    const float* __restrict__ skl_emd, const float* __restrict__ U,
    float* __restrict__ sklproj) {
  __shared__ float row[D_];
  const int s = blockIdx.x, h = threadIdx.x;
  if (h < D_) row[h] = skl_emd[s * D_ + h];
  __syncthreads();
  const float4* __restrict__ Urow = (const float4*)(U + (size_t)h * D_);
  float acc = 0.f;
#pragma unroll
  for (int i = 0; i < D_ / 4; i++) {
    const float4 u = Urow[i];
    acc += row[4 * i] * u.x;
    acc += row[4 * i + 1] * u.y;
    acc += row[4 * i + 2] * u.z;
    acc += row[4 * i + 3] * u.w;
  }
  sklproj[s * H_ + h] = acc;
}

// ---------------- Kernel B: att[p][k] = softmax_k( sum_h v[h]*tanh(projP[p][h]+sklproj[g[p][k]][h]) )
// R4: W row read as float4 (same fix as A). sklproj gathers are already
// lane-coalesced (h contiguous). Reduce + softmax unchanged.
__global__ __launch_bounds__(128) void att_kernel(
    const float* __restrict__ plm_emd, const float* __restrict__ W,
    const float* __restrict__ vT, const float* __restrict__ sklproj,
    const int* __restrict__ gidx, float* __restrict__ att) {
  __shared__ float prow[D_];
  __shared__ float red[2][K_];
  const int p = blockIdx.x, h = threadIdx.x;
  if (h < D_) prow[h] = plm_emd[p * D_ + h];
  __syncthreads();
  const float4* __restrict__ Wrow = (const float4*)(W + (size_t)h * D_);
  float pp = 0.f;
#pragma unroll
  for (int i = 0; i < D_ / 4; i++) {
    const float4 w = Wrow[i];
    pp += prow[4 * i] * w.x;
    pp += prow[4 * i + 1] * w.y;
    pp += prow[4 * i + 2] * w.z;
    pp += prow[4 * i + 3] * w.w;
  }
  const float v = vT[h];
  int g[K_];
#pragma unroll
  for (int k = 0; k < K_; k++) g[k] = gidx[p * K_ + k];
  float partial[K_];
#pragma unroll
  for (int k = 0; k < K_; k++) partial[k] = v * tanhf(pp + sklproj[g[k] * H_ + h]);
#pragma unroll
  for (int off = 32; off >= 1; off >>= 1)
#pragma unroll
    for (int k = 0; k < K_; k++) partial[k] += __shfl_down(partial[k], off, 64);
  const int wave = h >> 6, lane = h & 63;
  if (lane == 0)
#pragma unroll
    for (int k = 0; k < K_; k++) red[wave][k] = partial[k];
  __syncthreads();
  if (h == 0) {
    float s[K_], m = -1e30f;
#pragma unroll
    for (int k = 0; k < K_; k++) { s[k] = red[0][k] + red[1][k]; m = fmaxf(m, s[k]); }
    float denom = 0.f;
#pragma unroll
    for (int k = 0; k < K_; k++) { s[k] = expf(s[k] - m); denom += s[k]; }
    const float inv = 1.f / denom;
#pragma unroll
    for (int k = 0; k < K_; k++) att[p * K_ + k] = s[k] * inv;
  }
}

// ---------------- Kernel C: out[b][p] = mask[b][p] * sum_k skl_pfc[b][g[p][k]] * att[p][k]
// R3 structure kept (42.9 us): grid-stride 2 tiles/block, double-buffered LDS,
// reg prefetch of next tile during compute, att/gidx register-cached.
__global__ __launch_bounds__(256) void out_kernel(
    const float* __restrict__ skl_pfc, const float* __restrict__ mask,
    const float* __restrict__ att, const int* __restrict__ gidx,
    float* __restrict__ out) {
  __shared__ __align__(16) unsigned int rowsT[2][S_][PADU];  // 16384 B
  const int t = threadIdx.x;

  float aA[K_], aB[K_], aC[K_], aD[K_];
  int gA[K_], gB[K_], gC[K_], gD[K_];
  {
    const int pj0 = 2 * t, pj1 = 2 * t + 512;
    const float4* ap0 = (const float4*)(att + (size_t)pj0 * K_);
    const int4* gp0 = (const int4*)(gidx + (size_t)pj0 * K_);
    const float4* ap1 = (const float4*)(att + (size_t)pj1 * K_);
    const int4* gp1 = (const int4*)(gidx + (size_t)pj1 * K_);
    const float4 a0 = ap0[0], a1 = ap0[1], a2 = ap0[2], a3 = ap0[3];
    const int4 g0 = gp0[0], g1 = gp0[1], g2 = gp0[2], g3 = gp0[3];
    const float4 a4 = ap1[0], a5 = ap1[1], a6 = ap1[2], a7 = ap1[3];
    const int4 g4 = gp1[0], g5 = gp1[1], g6 = gp1[2], g7 = gp1[3];
    aA[0]=a0.x; aA[1]=a0.y; aA[2]=a0.z; aA[3]=a0.w; aA[4]=a1.x; aA[5]=a1.y; aA[6]=a1.z; aA[7]=a1.w;
    aB[0]=a2.x; aB[1]=a2.y; aB[2]=a2.z; aB[3]=a2.w; aB[4]=a3.x; aB[5]=a3.y; aB[6]=a3.z; aB[7]=a3.w;
    aC[0]=a4.x; aC[1]=a4.y; aC[2]=a4.z; aC[3]=a4.w; aC[4]=a5.x; aC[5]=a5.y; aC[6]=a5.z; aC[7]=a5.w;
    aD[0]=a6.x; aD[1]=a6.y; aD[2]=a6.z; aD[3]=a6.w; aD[4]=a7.x; aD[5]=a7.y; aD[6]=a7.z; aD[7]=a7.w;
    gA[0]=g0.x; gA[1]=g0.y; gA[2]=g0.z; gA[3]=g0.w; gA[4]=g1.x; gA[5]=g1.y; gA[6]=g1.z; gA[7]=g1.w;
    gB[0]=g2.x; gB[1]=g2.y; gB[2]=g2.z; gB[3]=g2.w; gB[4]=g3.x; gB[5]=g3.y; gB[6]=g3.z; gB[7]=g3.w;
    gC[0]=g4.x; gC[1]=g4.y; gC[2]=g4.z; gC[3]=g4.w; gC[4]=g5.x; gC[5]=g5.y; gC[6]=g5.z; gC[7]=g5.w;
    gD[0]=g6.x; gD[1]=g6.y; gD[2]=g6.z; gD[3]=g6.w; gD[4]=g7.x; gD[5]=g7.y; gD[6]=g7.z; gD[7]=g7.w;
  }

  float st[16];  // prefetch staging: [i*8 + b], i in {0,1} -> s = t + 256*i

  auto PREFETCH = [&](int tile) {
    const int b0 = tile * BT;
#pragma unroll
    for (int i = 0; i < 2; i++) {
      const int s = t + i * 256;
#pragma unroll
      for (int b = 0; b < 8; b++)
        st[i * 8 + b] =
            __builtin_nontemporal_load(&skl_pfc[(size_t)(b0 + b) * S_ + s]);
    }
  };

  auto PACK = [&](int buf) {
#pragma unroll
    for (int i = 0; i < 2; i++) {
      const int s = t + i * 256;
      unsigned int pk[PADU];
#pragma unroll
      for (int q = 0; q < PADU; q++)
        pk[q] = rne16(st[i * 8 + 2 * q]) | (rne16(st[i * 8 + 2 * q + 1]) << 16);
      *(uint4*)&rowsT[buf][s][0] = make_uint4(pk[0], pk[1], pk[2], pk[3]);
    }
  };

  auto COMPUTE = [&](int tile, int buf) {
    const int b0 = tile * BT;
#pragma unroll
    for (int j = 0; j < 2; j++) {
      const int p = 2 * t + j * 512;
      const float* av0 = (j == 0) ? aA : aC;
      const float* av1 = (j == 0) ? aB : aD;
      const int* gv0 = (j == 0) ? gA : gC;
      const int* gv1 = (j == 0) ? gB : gD;

      f32x2 m2[BT];
#pragma unroll
      for (int bb = 0; bb < BT; bb++)
        m2[bb] = __builtin_nontemporal_load(
            (const f32x2*)&mask[(size_t)(b0 + bb) * P_ + p]);

      float acc0[BT] = {0.f, 0.f, 0.f, 0.f, 0.f, 0.f, 0.f, 0.f};
      float acc1[BT] = {0.f, 0.f, 0.f, 0.f, 0.f, 0.f, 0.f, 0.f};
#pragma unroll
      for (int k = 0; k < K_; k++) {
        const uint4 q0 = *(const uint4*)&rowsT[buf][gv0[k]][0];
        const float a = av0[k];
        acc0[0] += bflo(q0.x) * a; acc0[1] += bfhi(q0.x) * a;
        acc0[2] += bflo(q0.y) * a; acc0[3] += bfhi(q0.y) * a;
        acc0[4] += bflo(q0.z) * a; acc0[5] += bfhi(q0.z) * a;
        acc0[6] += bflo(q0.w) * a; acc0[7] += bfhi(q0.w) * a;
      }
#pragma unroll
      for (int k = 0; k < K_; k++) {
        const uint4 q1 = *(const uint4*)&rowsT[buf][gv1[k]][0];
        const float a = av1[k];
        acc1[0] += bflo(q1.x) * a; acc1[1] += bfhi(q1.x) * a;
        acc1[2] += bflo(q1.y) * a; acc1[3] += bfhi(q1.y) * a;
        acc1[4] += bflo(q1.z) * a; acc1[5] += bfhi(q1.z) * a;
        acc1[6] += bflo(q1.w) * a; acc1[7] += bfhi(q1.w) * a;
      }
#pragma unroll
      for (int bb = 0; bb < BT; bb++) {
        f32x2 o;
        o.x = acc0[bb] * m2[bb].x;
        o.y = acc1[bb] * m2[bb].y;
        __builtin_nontemporal_store(o, (f32x2*)&out[(size_t)(b0 + bb) * P_ + p]);
      }
    }
  };

  int tile = blockIdx.x;
  int buf = 0;
  PREFETCH(tile);
  for (;;) {
    PACK(buf);            // waits on prefetch loads (vmcnt auto)
    __syncthreads();      // tile's LDS buffer ready for all waves
    const int next = tile + GRID_C;
    if (next < NT) PREFETCH(next);  // HBM stream overlaps compute below
    COMPUTE(tile, buf);
    if (next >= NT) break;
    tile = next;
    buf ^= 1;
  }
}

extern "C" void kernel_launch(void* const* d_in, const int* in_sizes, int n_in,
                              void* d_out, int out_size, void* d_ws, size_t ws_size,
                              hipStream_t stream) {
  const float* skl_pfc = (const float*)d_in[0];   // [B, S]
  const float* mask    = (const float*)d_in[1];   // [B, P]
  const float* skl_emd = (const float*)d_in[2];   // [S, D]
  const float* plm_emd = (const float*)d_in[3];   // [P, D]
  const float* W       = (const float*)d_in[4];   // [H, D]
  const float* U       = (const float*)d_in[5];   // [H, D]
  const float* vT      = (const float*)d_in[6];   // [1, H]
  const int*   gidx    = (const int*)d_in[7];     // [P, K]
  float* out = (float*)d_out;                     // [B, P]

  float* sklproj = (float*)d_ws;                  // S*H floats = 256 KB
  float* att     = sklproj + S_ * H_;             // P*K floats = 32 KB

  proj_skl_kernel<<<S_, 128, 0, stream>>>(skl_emd, U, sklproj);
  att_kernel<<<P_, 128, 0, stream>>>(plm_emd, W, vT, sklproj, gidx, att);
  out_kernel<<<GRID_C, 256, 0, stream>>>(skl_pfc, mask, att, gidx, out);
}

// Round 5
// 164.813 us; speedup vs baseline: 1.0361x; 1.0085x over previous
//
#include <hip/hip_runtime.h>
#include <cmath>

#define B_ 16384
#define S_ 512
#define P_ 1024
#define K_ 8
#define D_ 64
#define H_ 128
#define BT 8       // batch rows per tile; bf16-packed tile = 512*4*4B = 8 KB
#define PADU 4     // u32 per LDS row (4 u32 = 8 bf16 batch values), 16B-aligned for b128
#define GRID_C 512           // blocks for out_kernel; each handles NT/GRID_C = 4 tiles
#define NT (B_ / BT)         // 2048 b-tiles

typedef float f32x2 __attribute__((ext_vector_type(2)));  // clang vector: OK for nontemporal builtins

// float -> bf16 (RNE, finite inputs) packed helpers
static __device__ __forceinline__ unsigned int rne16(float f) {
  unsigned int u = __float_as_uint(f);
  return (u + 0x7fffu + ((u >> 16) & 1u)) >> 16;
}
static __device__ __forceinline__ float bflo(unsigned int u) { return __uint_as_float(u << 16); }
static __device__ __forceinline__ float bfhi(unsigned int u) { return __uint_as_float(u & 0xffff0000u); }

// ---------------- Kernel A: sklproj[s][h] = dot(skl_emd[s,:], U[h,:]) ----------------
__global__ __launch_bounds__(128) void proj_skl_kernel(
    const float* __restrict__ skl_emd, const float* __restrict__ U,
    float* __restrict__ sklproj) {
  __shared__ float row[D_];
  const int s = blockIdx.x, h = threadIdx.x;
  if (h < D_) row[h] = skl_emd[s * D_ + h];
  __syncthreads();
  const float4* __restrict__ Urow = (const float4*)(U + (size_t)h * D_);
  float acc = 0.f;
#pragma unroll
  for (int i = 0; i < D_ / 4; i++) {
    const float4 u = Urow[i];
    acc += row[4 * i] * u.x;
    acc += row[4 * i + 1] * u.y;
    acc += row[4 * i + 2] * u.z;
    acc += row[4 * i + 3] * u.w;
  }
  sklproj[s * H_ + h] = acc;
}

// ---------------- Kernel B: att[p][k] = softmax_k( sum_h v[h]*tanh(projP[p][h]+sklproj[g[p][k]][h]) )
__global__ __launch_bounds__(128) void att_kernel(
    const float* __restrict__ plm_emd, const float* __restrict__ W,
    const float* __restrict__ vT, const float* __restrict__ sklproj,
    const int* __restrict__ gidx, float* __restrict__ att) {
  __shared__ float prow[D_];
  __shared__ float red[2][K_];
  const int p = blockIdx.x, h = threadIdx.x;
  if (h < D_) prow[h] = plm_emd[p * D_ + h];
  __syncthreads();
  const float4* __restrict__ Wrow = (const float4*)(W + (size_t)h * D_);
  float pp = 0.f;
#pragma unroll
  for (int i = 0; i < D_ / 4; i++) {
    const float4 w = Wrow[i];
    pp += prow[4 * i] * w.x;
    pp += prow[4 * i + 1] * w.y;
    pp += prow[4 * i + 2] * w.z;
    pp += prow[4 * i + 3] * w.w;
  }
  const float v = vT[h];
  int g[K_];
#pragma unroll
  for (int k = 0; k < K_; k++) g[k] = gidx[p * K_ + k];
  float partial[K_];
#pragma unroll
  for (int k = 0; k < K_; k++) partial[k] = v * tanhf(pp + sklproj[g[k] * H_ + h]);
#pragma unroll
  for (int off = 32; off >= 1; off >>= 1)
#pragma unroll
    for (int k = 0; k < K_; k++) partial[k] += __shfl_down(partial[k], off, 64);
  const int wave = h >> 6, lane = h & 63;
  if (lane == 0)
#pragma unroll
    for (int k = 0; k < K_; k++) red[wave][k] = partial[k];
  __syncthreads();
  if (h == 0) {
    float s[K_], m = -1e30f;
#pragma unroll
    for (int k = 0; k < K_; k++) { s[k] = red[0][k] + red[1][k]; m = fmaxf(m, s[k]); }
    float denom = 0.f;
#pragma unroll
    for (int k = 0; k < K_; k++) { s[k] = expf(s[k] - m); denom += s[k]; }
    const float inv = 1.f / denom;
#pragma unroll
    for (int k = 0; k < K_; k++) att[p * K_ + k] = s[k] * inv;
  }
}

// ---------------- Kernel C: out[b][p] = mask[b][p] * sum_k skl_pfc[b][g[p][k]] * att[p][k]
// R5: 512-thread blocks (8 waves), GRID_C=512 x 4 tiles/block (3/4 pipeline-
// overlapped), each thread stages ONE LDS row (8 loads -> 1 uint4 write; was 2
// rows/16 loads) and owns p=2t,2t+1 (no j-loop). att/gidx register-cached
// (tile-invariant). Double-buffered 2x8KB LDS, one barrier per tile.
// Watch: VGPR>128 or FETCH growth -> spills, revert.
__global__ __launch_bounds__(512) void out_kernel(
    const float* __restrict__ skl_pfc, const float* __restrict__ mask,
    const float* __restrict__ att, const int* __restrict__ gidx,
    float* __restrict__ out) {
  __shared__ __align__(16) unsigned int rowsT[2][S_][PADU];  // 16384 B
  const int t = threadIdx.x;      // 0..511
  const int p2 = 2 * t;           // this thread's p pair: p2, p2+1

  // ---- register-cache att + gidx for this thread's 2 p's (tile-invariant) ----
  float aA[K_], aB[K_];
  int gA[K_], gB[K_];
  {
    const float4* ap = (const float4*)(att + (size_t)p2 * K_);
    const int4* gp = (const int4*)(gidx + (size_t)p2 * K_);
    const float4 a0 = ap[0], a1 = ap[1], a2 = ap[2], a3 = ap[3];
    const int4 g0 = gp[0], g1 = gp[1], g2 = gp[2], g3 = gp[3];
    aA[0]=a0.x; aA[1]=a0.y; aA[2]=a0.z; aA[3]=a0.w; aA[4]=a1.x; aA[5]=a1.y; aA[6]=a1.z; aA[7]=a1.w;
    aB[0]=a2.x; aB[1]=a2.y; aB[2]=a2.z; aB[3]=a2.w; aB[4]=a3.x; aB[5]=a3.y; aB[6]=a3.z; aB[7]=a3.w;
    gA[0]=g0.x; gA[1]=g0.y; gA[2]=g0.z; gA[3]=g0.w; gA[4]=g1.x; gA[5]=g1.y; gA[6]=g1.z; gA[7]=g1.w;
    gB[0]=g2.x; gB[1]=g2.y; gB[2]=g2.z; gB[3]=g2.w; gB[4]=g3.x; gB[5]=g3.y; gB[6]=g3.z; gB[7]=g3.w;
  }

  float st[BT];  // prefetch staging for LDS row s = t

  // issue prefetch for a tile's skl_pfc rows (touch-once stream): row s = t
  auto PREFETCH = [&](int tile) {
    const int b0 = tile * BT;
#pragma unroll
    for (int b = 0; b < BT; b++)
      st[b] = __builtin_nontemporal_load(&skl_pfc[(size_t)(b0 + b) * S_ + t]);
  };

  // bf16-pack staged regs and write transposed row into LDS buffer
  auto PACK = [&](int buf) {
    unsigned int pk[PADU];
#pragma unroll
    for (int q = 0; q < PADU; q++)
      pk[q] = rne16(st[2 * q]) | (rne16(st[2 * q + 1]) << 16);
    *(uint4*)&rowsT[buf][t][0] = make_uint4(pk[0], pk[1], pk[2], pk[3]);
  };

  auto COMPUTE = [&](int tile, int buf) {
    const int b0 = tile * BT;
    f32x2 m2[BT];
#pragma unroll
    for (int bb = 0; bb < BT; bb++)
      m2[bb] = __builtin_nontemporal_load(
          (const f32x2*)&mask[(size_t)(b0 + bb) * P_ + p2]);

    float acc0[BT] = {0.f, 0.f, 0.f, 0.f, 0.f, 0.f, 0.f, 0.f};
    float acc1[BT] = {0.f, 0.f, 0.f, 0.f, 0.f, 0.f, 0.f, 0.f};
#pragma unroll
    for (int k = 0; k < K_; k++) {
      const uint4 q0 = *(const uint4*)&rowsT[buf][gA[k]][0];  // bb 0..7 packed bf16
      const float a = aA[k];
      acc0[0] += bflo(q0.x) * a; acc0[1] += bfhi(q0.x) * a;
      acc0[2] += bflo(q0.y) * a; acc0[3] += bfhi(q0.y) * a;
      acc0[4] += bflo(q0.z) * a; acc0[5] += bfhi(q0.z) * a;
      acc0[6] += bflo(q0.w) * a; acc0[7] += bfhi(q0.w) * a;
    }
#pragma unroll
    for (int k = 0; k < K_; k++) {
      const uint4 q1 = *(const uint4*)&rowsT[buf][gB[k]][0];
      const float a = aB[k];
      acc1[0] += bflo(q1.x) * a; acc1[1] += bfhi(q1.x) * a;
      acc1[2] += bflo(q1.y) * a; acc1[3] += bfhi(q1.y) * a;
      acc1[4] += bflo(q1.z) * a; acc1[5] += bfhi(q1.z) * a;
      acc1[6] += bflo(q1.w) * a; acc1[7] += bfhi(q1.w) * a;
    }
#pragma unroll
    for (int bb = 0; bb < BT; bb++) {
      f32x2 o;
      o.x = acc0[bb] * m2[bb].x;
      o.y = acc1[bb] * m2[bb].y;
      __builtin_nontemporal_store(o, (f32x2*)&out[(size_t)(b0 + bb) * P_ + p2]);
    }
  };

  // ---- software pipeline over 4 tiles ----
  int tile = blockIdx.x;
  int buf = 0;
  PREFETCH(tile);
  for (;;) {
    PACK(buf);            // waits on prefetch loads (vmcnt auto)
    __syncthreads();      // tile's LDS buffer ready for all waves
    const int next = tile + GRID_C;
    if (next < NT) PREFETCH(next);  // HBM stream overlaps compute below
    COMPUTE(tile, buf);
    if (next >= NT) break;
    tile = next;
    buf ^= 1;
  }
}

extern "C" void kernel_launch(void* const* d_in, const int* in_sizes, int n_in,
                              void* d_out, int out_size, void* d_ws, size_t ws_size,
                              hipStream_t stream) {
  const float* skl_pfc = (const float*)d_in[0];   // [B, S]
  const float* mask    = (const float*)d_in[1];   // [B, P]
  const float* skl_emd = (const float*)d_in[2];   // [S, D]
  const float* plm_emd = (const float*)d_in[3];   // [P, D]
  const float* W       = (const float*)d_in[4];   // [H, D]
  const float* U       = (const float*)d_in[5];   // [H, D]
  const float* vT      = (const float*)d_in[6];   // [1, H]
  const int*   gidx    = (const int*)d_in[7];     // [P, K]
  float* out = (float*)d_out;                     // [B, P]

  float* sklproj = (float*)d_ws;                  // S*H floats = 256 KB
  float* att     = sklproj + S_ * H_;             // P*K floats = 32 KB

  proj_skl_kernel<<<S_, 128, 0, stream>>>(skl_emd, U, sklproj);
  att_kernel<<<P_, 128, 0, stream>>>(plm_emd, W, vT, sklproj, gidx, att);
  out_kernel<<<GRID_C, 512, 0, stream>>>(skl_pfc, mask, att, gidx, out);
}